// Round 12
// baseline (402.090 us; speedup 1.0000x reference)
//
#include <hip/hip_runtime.h>
#include <math.h>

#define N_NODES 20000
#define N_EDGES 640000

typedef __attribute__((ext_vector_type(8))) short short8;
typedef __attribute__((ext_vector_type(4))) float floatx4;
typedef __attribute__((ext_vector_type(2))) float float2v;

__device__ __forceinline__ float elu_f(float v) { return v > 0.f ? v : expm1f(v); }

__device__ __forceinline__ unsigned short bf16_rne(float f) {
  union { float f; unsigned u; } v;
  v.f = f;
  unsigned r = v.u + 0x7FFF + ((v.u >> 16) & 1);
  return (unsigned short)(r >> 16);
}

// unpack a dword holding two bf16 (lo = elem0, hi = elem1) into packed f32 pair
__device__ __forceinline__ float2v unpack_bf2(unsigned u) {
  union { unsigned u; float f; } lo, hi;
  lo.u = u << 16;
  hi.u = u & 0xffff0000u;
  return (float2v){lo.f, hi.f};
}

// bank-swizzle within 8-element groups (writer 8-strided and reader both conflict-free)
__device__ __forceinline__ int swz(int c) {
  return (c & ~7) | ((((c & 7) + ((c >> 3) >> 2))) & 7);
}

// ---------------- CSR build ----------------

__global__ void hist_kernel(const int* __restrict__ dst, int* __restrict__ cnt, int ne) {
  int e = blockIdx.x * 256 + threadIdx.x;
  if (e < ne) atomicAdd(&cnt[dst[e]], 1);
}

__global__ __launch_bounds__(1024) void scan_kernel(const int* __restrict__ cnt,
                                                    int* __restrict__ row_ptr,
                                                    int* __restrict__ row_next, int n) {
  __shared__ int part[1024];
  int t = threadIdx.x;
  int per = (n + 1023) / 1024;
  int base = t * per;
  int local = 0;
  for (int i = 0; i < per; ++i) {
    int idx = base + i;
    if (idx < n) local += cnt[idx];
  }
  part[t] = local;
  __syncthreads();
  for (int off = 1; off < 1024; off <<= 1) {
    int v = (t >= off) ? part[t - off] : 0;
    __syncthreads();
    part[t] += v;
    __syncthreads();
  }
  int prefix = (t == 0) ? 0 : part[t - 1];
  for (int i = 0; i < per; ++i) {
    int idx = base + i;
    if (idx < n) {
      row_ptr[idx] = prefix;
      row_next[idx] = prefix;
      prefix += cnt[idx];
    }
  }
  if (t == 1023) row_ptr[n] = part[1023];
}

__global__ void fill_kernel(const int* __restrict__ dst, int* __restrict__ row_next,
                            int* __restrict__ csr_eid, int ne) {
  int e = blockIdx.x * 256 + threadIdx.x;
  if (e >= ne) return;
  int pos = atomicAdd(&row_next[dst[e]], 1);
  csr_eid[pos] = e;
}

// ---------------- prep_all: in_proj (0..4999) + wt cast (5000..5383) + edge prep (5384+) ---
// edot layout: edot12[layer][i*4+h] interleaved (coalesced float4/edge), edot3[i] plane.

__global__ void prep_all_kernel(const float* __restrict__ x, const float* __restrict__ Wp,
                                const float* __restrict__ bp, unsigned short* __restrict__ h_bf,
                                const float* __restrict__ W1, const float* __restrict__ W2,
                                const float* __restrict__ W3, unsigned short* __restrict__ Bt1,
                                unsigned short* __restrict__ Bt2, unsigned short* __restrict__ Bt3,
                                const float* __restrict__ We1, const float* __restrict__ ae1,
                                const float* __restrict__ We2, const float* __restrict__ ae2,
                                const float* __restrict__ We3, const float* __restrict__ ae3,
                                const int* __restrict__ csr_eid, const int* __restrict__ src,
                                const float* __restrict__ ea, int* __restrict__ csr_src,
                                float* __restrict__ edot1, float* __restrict__ edot2,
                                float* __restrict__ edot3) {
  int b = blockIdx.x, t = threadIdx.x;
  if (b < 5000) {
    int i = b * 256 + t;
    int node = i >> 6, c = i & 63;
    float v = x[node * 2] * Wp[c] + x[node * 2 + 1] * Wp[64 + c] + bp[c];
    h_bf[i] = bf16_rne(elu_f(v));
  } else if (b < 5384) {
    int idx = (b - 5000) * 256 + t;
    const float* W; unsigned short* Bt; int K, Nc, local;
    if (idx < 16384)      { W = W1; Bt = Bt1; K = 64;  Nc = 256; local = idx; }
    else if (idx < 81920) { W = W2; Bt = Bt2; K = 256; Nc = 256; local = idx - 16384; }
    else if (idx < 98304) { W = W3; Bt = Bt3; K = 256; Nc = 64;  local = idx - 81920; }
    else return;
    int k = local / Nc, n = local - k * Nc;
    Bt[(size_t)n * K + k] = bf16_rne(W[local]);
  } else {
    __shared__ float pj[27];
    if (t < 12) {
      int d = t >> 2, h = t & 3;
      float s = 0.f;
      for (int c = 0; c < 64; ++c) s += We1[d * 256 + h * 64 + c] * ae1[h * 64 + c];
      pj[t] = s;
    } else if (t < 24) {
      int u = t - 12; int d = u >> 2, h = u & 3;
      float s = 0.f;
      for (int c = 0; c < 64; ++c) s += We2[d * 256 + h * 64 + c] * ae2[h * 64 + c];
      pj[12 + u] = s;
    } else if (t < 27) {
      int d = t - 24;
      float s = 0.f;
      for (int c = 0; c < 64; ++c) s += We3[d * 64 + c] * ae3[c];
      pj[24 + d] = s;
    }
    __syncthreads();
    int i = (b - 5384) * 256 + t;
    if (i >= N_EDGES) return;
    int eid = csr_eid[i];
    csr_src[i] = src[eid];
    float e0 = ea[eid * 3 + 0], e1 = ea[eid * 3 + 1], e2 = ea[eid * 3 + 2];
    float4 v1, v2;
    v1.x = e0 * pj[0] + e1 * pj[4] + e2 * pj[8];
    v1.y = e0 * pj[1] + e1 * pj[5] + e2 * pj[9];
    v1.z = e0 * pj[2] + e1 * pj[6] + e2 * pj[10];
    v1.w = e0 * pj[3] + e1 * pj[7] + e2 * pj[11];
    v2.x = e0 * pj[12] + e1 * pj[16] + e2 * pj[20];
    v2.y = e0 * pj[13] + e1 * pj[17] + e2 * pj[21];
    v2.z = e0 * pj[14] + e1 * pj[18] + e2 * pj[22];
    v2.w = e0 * pj[15] + e1 * pj[19] + e2 * pj[23];
    *(float4*)(edot1 + (size_t)i * 4) = v1;
    *(float4*)(edot2 + (size_t)i * 4) = v2;
    edot3[i] = e0 * pj[24] + e1 * pj[25] + e2 * pj[26];
  }
}

// ---------------- MFMA bf16 GEMM + fused alpha epilogue ----------------------------

template <int KDIM>
__global__ __launch_bounds__(256) void mfma_gemm_alpha_kernel(
    const unsigned short* __restrict__ A, const unsigned short* __restrict__ Bt,
    unsigned short* __restrict__ C_bf, const float* __restrict__ a_src,
    const float* __restrict__ a_dst, float* __restrict__ alp_s,
    float* __restrict__ alp_d, int M, int Nc) {
  __shared__ unsigned short As[64][40];
  __shared__ unsigned short Bs[64][40];
  int t = threadIdx.x;
  int wave = t >> 6, lane = t & 63;
  int m_frag = lane & 15, quad = lane >> 4;
  int row0 = blockIdx.y * 64, col0 = blockIdx.x * 64;
  int lr = t >> 2;
  int lk = (t & 3) * 8;
  floatx4 acc[4];
  #pragma unroll
  for (int c = 0; c < 4; ++c) acc[c] = (floatx4){0.f, 0.f, 0.f, 0.f};

  for (int k0 = 0; k0 < KDIM; k0 += 32) {
    int gr = row0 + lr;
    short8 av = {0, 0, 0, 0, 0, 0, 0, 0};
    if (gr < M) av = *(const short8*)(A + (size_t)gr * KDIM + k0 + lk);
    *(short8*)(&As[lr][lk]) = av;
    short8 bv = *(const short8*)(Bt + (size_t)(col0 + lr) * KDIM + k0 + lk);
    *(short8*)(&Bs[lr][lk]) = bv;
    __syncthreads();
    short8 a = *(const short8*)(&As[wave * 16 + m_frag][quad * 8]);
    #pragma unroll
    for (int c = 0; c < 4; ++c) {
      short8 b = *(const short8*)(&Bs[c * 16 + m_frag][quad * 8]);
      acc[c] = __builtin_amdgcn_mfma_f32_16x16x32_bf16(a, b, acc[c], 0, 0, 0);
    }
    __syncthreads();
  }

  int H = Nc >> 6;
  int head = blockIdx.x;
  float ps[4] = {}, pd[4] = {};
  #pragma unroll
  for (int c = 0; c < 4; ++c) {
    float asv = a_src[head * 64 + c * 16 + m_frag];
    float adv = a_dst[head * 64 + c * 16 + m_frag];
    #pragma unroll
    for (int i = 0; i < 4; ++i) {
      ps[i] += acc[c][i] * asv;
      pd[i] += acc[c][i] * adv;
    }
  }
  #pragma unroll
  for (int off = 1; off < 16; off <<= 1) {
    #pragma unroll
    for (int i = 0; i < 4; ++i) {
      ps[i] += __shfl_xor(ps[i], off);
      pd[i] += __shfl_xor(pd[i], off);
    }
  }
  #pragma unroll
  for (int c = 0; c < 4; ++c) {
    #pragma unroll
    for (int i = 0; i < 4; ++i) {
      int gr = row0 + wave * 16 + quad * 4 + i;
      if (gr < M) C_bf[(size_t)gr * Nc + col0 + c * 16 + m_frag] = bf16_rne(acc[c][i]);
    }
  }
  if (m_frag == 0) {
    #pragma unroll
    for (int i = 0; i < 4; ++i) {
      int gr = row0 + wave * 16 + quad * 4 + i;
      if (gr < M) {
        alp_s[gr * H + head] = ps[i];
        alp_d[gr * H + head] = pd[i];
      }
    }
  }
}

// ---------------- fused softmax + aggregate, H=4 (block per node) -------------------
// Phase 1: thread-per-edge, ALL 4 heads at once — 2 global loads/edge (alp_s float4
// gather + edot float4 coalesced) vs 12 in the per-wave-per-head form. lds_w is
// [CHUNK][4]: writer = contiguous b128, reader = 8 slots x 4 heads = banks 0..31.
// Phase 2: proven R8/R11 shape (L=32, S=8, accp[4], 2-edge unroll).

template <bool OUT_BF>
__global__ __launch_bounds__(256) void softagg4_kernel(
    const int* __restrict__ row_ptr, const int* __restrict__ csr_src,
    const float* __restrict__ edot, const float* __restrict__ alp_s,
    const float* __restrict__ alp_d, const unsigned short* __restrict__ xh_bf,
    const float* __restrict__ bias, float* __restrict__ out,
    unsigned short* __restrict__ out_bf) {
  constexpr int HC = 256, CHUNK = 256, L = 32, S = 8;
  __shared__ float lds_w[CHUNK * 4];      // [edge][head]
  __shared__ int lds_src[CHUNK];
  __shared__ float sh_part[4][4];         // [wave][head]
  __shared__ float sh_inv[4];
  __shared__ float red[4 * HC];

  int n = blockIdx.x;
  int t = threadIdx.x;
  int wave = t >> 6, lane = t & 63;
  int slot = t / L, l = t % L;            // 8 slots x 32 lanes; lane covers ch [l*8, l*8+8)
  int head2 = l >> 3;
  int s0 = row_ptr[n], s1 = row_ptr[n + 1];

  float4 adv4 = *(const float4*)(alp_d + n * 4);
  float s_acc[4] = {};
  float2v accp[4] = {};

  for (int c0 = s0; c0 < s1; c0 += CHUNK) {
    int cend = min(s1, c0 + CHUNK);
    int i = c0 + t;                       // one edge per thread, all 4 heads
    if (i < cend) {
      int s = csr_src[i];
      lds_src[t] = s;
      float4 as4 = *(const float4*)(alp_s + s * 4);
      float4 ed4 = *(const float4*)(edot + (size_t)i * 4);
      float a0 = as4.x + adv4.x + ed4.x;
      float a1 = as4.y + adv4.y + ed4.y;
      float a2 = as4.z + adv4.z + ed4.z;
      float a3 = as4.w + adv4.w + ed4.w;
      a0 = a0 > 0.f ? a0 : 0.2f * a0;
      a1 = a1 > 0.f ? a1 : 0.2f * a1;
      a2 = a2 > 0.f ? a2 : 0.2f * a2;
      a3 = a3 > 0.f ? a3 : 0.2f * a3;
      float4 w4;
      w4.x = __expf(fminf(a0, 30.f));
      w4.y = __expf(fminf(a1, 30.f));
      w4.z = __expf(fminf(a2, 30.f));
      w4.w = __expf(fminf(a3, 30.f));
      *(float4*)(lds_w + t * 4) = w4;
      s_acc[0] += w4.x; s_acc[1] += w4.y; s_acc[2] += w4.z; s_acc[3] += w4.w;
    }
    __syncthreads();
    // 2-edge unrolled gather: two loads in flight per thread
    int j = c0 + slot;
    for (; j + S < cend; j += 2 * S) {
      int sA = lds_src[j - c0];
      int sB = lds_src[j - c0 + S];
      float wA = lds_w[(j - c0) * 4 + head2];
      float wB = lds_w[(j - c0 + S) * 4 + head2];
      uint4 uA = *(const uint4*)(xh_bf + (size_t)sA * HC + l * 8);
      uint4 uB = *(const uint4*)(xh_bf + (size_t)sB * HC + l * 8);
      float2v wAp = {wA, wA}, wBp = {wB, wB};
      accp[0] = __builtin_elementwise_fma(unpack_bf2(uA.x), wAp, accp[0]);
      accp[1] = __builtin_elementwise_fma(unpack_bf2(uA.y), wAp, accp[1]);
      accp[2] = __builtin_elementwise_fma(unpack_bf2(uA.z), wAp, accp[2]);
      accp[3] = __builtin_elementwise_fma(unpack_bf2(uA.w), wAp, accp[3]);
      accp[0] = __builtin_elementwise_fma(unpack_bf2(uB.x), wBp, accp[0]);
      accp[1] = __builtin_elementwise_fma(unpack_bf2(uB.y), wBp, accp[1]);
      accp[2] = __builtin_elementwise_fma(unpack_bf2(uB.z), wBp, accp[2]);
      accp[3] = __builtin_elementwise_fma(unpack_bf2(uB.w), wBp, accp[3]);
    }
    if (j < cend) {
      int s = lds_src[j - c0];
      float w = lds_w[(j - c0) * 4 + head2];
      uint4 u = *(const uint4*)(xh_bf + (size_t)s * HC + l * 8);
      float2v wp = {w, w};
      accp[0] = __builtin_elementwise_fma(unpack_bf2(u.x), wp, accp[0]);
      accp[1] = __builtin_elementwise_fma(unpack_bf2(u.y), wp, accp[1]);
      accp[2] = __builtin_elementwise_fma(unpack_bf2(u.z), wp, accp[2]);
      accp[3] = __builtin_elementwise_fma(unpack_bf2(u.w), wp, accp[3]);
    }
    __syncthreads();
  }
  // reduce per-head exp sums: butterfly within wave, then across 4 waves via LDS
  #pragma unroll
  for (int off = 1; off < 64; off <<= 1) {
    #pragma unroll
    for (int h = 0; h < 4; ++h) s_acc[h] += __shfl_xor(s_acc[h], off);
  }
  if (lane == 0) {
    #pragma unroll
    for (int h = 0; h < 4; ++h) sh_part[wave][h] = s_acc[h];
  }
  __syncthreads();
  if (t < 4) {
    float s = sh_part[0][t] + sh_part[1][t] + sh_part[2][t] + sh_part[3][t];
    sh_inv[t] = 1.0f / (s + 1e-16f);
  }
  __syncthreads();
  float2v invp = {sh_inv[head2], sh_inv[head2]};
  #pragma unroll
  for (int d = 0; d < 4; ++d) accp[d] *= invp;
  float accf[8];
  #pragma unroll
  for (int d = 0; d < 4; ++d) { accf[2 * d] = accp[d].x; accf[2 * d + 1] = accp[d].y; }
  // reduce slots within wave (slots stride L=32 lanes)
  #pragma unroll
  for (int off = L; off < 64; off <<= 1) {
    #pragma unroll
    for (int j = 0; j < 8; ++j) accf[j] += __shfl_xor(accf[j], off);
  }
  if (lane < L) {
    #pragma unroll
    for (int j = 0; j < 8; ++j) red[wave * HC + swz(lane * 8 + j)] = accf[j];
  }
  __syncthreads();
  {
    int pos = swz(t);
    float a = red[0 * HC + pos] + red[1 * HC + pos] + red[2 * HC + pos] + red[3 * HC + pos];
    a += bias[t];
    a = elu_f(a);
    if (OUT_BF) out_bf[(size_t)n * HC + t] = bf16_rne(a);
    else out[(size_t)n * HC + t] = a;
  }
}

// ---------------- layer-3 softagg (wave per node, H=1, HC=64) + fused classifier ----

__global__ __launch_bounds__(256) void softagg_cls_kernel(
    const int* __restrict__ row_ptr, const int* __restrict__ csr_src,
    const float* __restrict__ edot, const float* __restrict__ alp_s,
    const float* __restrict__ alp_d, const unsigned short* __restrict__ xh_bf,
    const float* __restrict__ b3, const float* __restrict__ Wc,
    const float* __restrict__ bc, float* __restrict__ out, int n_nodes) {
  constexpr int CHUNK = 256;
  __shared__ float lds_w[4][CHUNK];
  __shared__ int lds_s[4][CHUNK];

  int wave = threadIdx.x >> 6, lane = threadIdx.x & 63;
  int n = blockIdx.x * 4 + wave;
  if (n >= n_nodes) return;
  int slot = lane >> 3, l = lane & 7;
  int s0 = row_ptr[n], s1 = row_ptr[n + 1];

  float s_run = 0.f;
  float2v accp[4] = {};
  float adv = alp_d[n];

  for (int c0 = s0; c0 < s1; c0 += CHUNK) {
    int cend = min(s1, c0 + CHUNK);
    float se = 0.f;
    for (int i = c0 + lane; i < cend; i += 64) {
      int s = csr_src[i];
      lds_s[wave][i - c0] = s;
      float a = alp_s[s] + adv + edot[i];
      a = a > 0.f ? a : 0.2f * a;
      float w = __expf(fminf(a, 30.f));
      lds_w[wave][i - c0] = w;
      se += w;
    }
    #pragma unroll
    for (int off = 1; off < 64; off <<= 1) se += __shfl_xor(se, off);
    s_run += se;
    for (int i = c0 + slot; i < cend; i += 8) {
      int s = lds_s[wave][i - c0];
      float w = lds_w[wave][i - c0];
      uint4 u = *(const uint4*)(xh_bf + (size_t)s * 64 + l * 8);
      float2v wp = {w, w};
      accp[0] = __builtin_elementwise_fma(unpack_bf2(u.x), wp, accp[0]);
      accp[1] = __builtin_elementwise_fma(unpack_bf2(u.y), wp, accp[1]);
      accp[2] = __builtin_elementwise_fma(unpack_bf2(u.z), wp, accp[2]);
      accp[3] = __builtin_elementwise_fma(unpack_bf2(u.w), wp, accp[3]);
    }
  }
  float inv = 1.0f / (s_run + 1e-16f);
  float2v invp = {inv, inv};
  #pragma unroll
  for (int d = 0; d < 4; ++d) accp[d] *= invp;
  float accf[8];
  #pragma unroll
  for (int d = 0; d < 4; ++d) { accf[2 * d] = accp[d].x; accf[2 * d + 1] = accp[d].y; }
  #pragma unroll
  for (int off = 8; off < 64; off <<= 1) {
    #pragma unroll
    for (int j = 0; j < 8; ++j) accf[j] += __shfl_xor(accf[j], off);
  }
  float p0 = 0.f, p1 = 0.f, p2 = 0.f, p3 = 0.f;
  #pragma unroll
  for (int j = 0; j < 8; ++j) {
    int c = l * 8 + j;
    float v = accf[j] + b3[c];
    p0 += v * Wc[c * 4 + 0];
    p1 += v * Wc[c * 4 + 1];
    p2 += v * Wc[c * 4 + 2];
    p3 += v * Wc[c * 4 + 3];
  }
  #pragma unroll
  for (int off = 1; off < 8; off <<= 1) {
    p0 += __shfl_xor(p0, off);
    p1 += __shfl_xor(p1, off);
    p2 += __shfl_xor(p2, off);
    p3 += __shfl_xor(p3, off);
  }
  if (lane == 0) {
    p0 += bc[0]; p1 += bc[1]; p2 += bc[2]; p3 += bc[3];
    float mx = fmaxf(fmaxf(p0, p1), fmaxf(p2, p3));
    float e0 = __expf(p0 - mx), e1 = __expf(p1 - mx), e2 = __expf(p2 - mx), e3 = __expf(p3 - mx);
    float s = 1.f / (e0 + e1 + e2 + e3);
    out[n * 4 + 0] = e0 * s;
    out[n * 4 + 1] = e1 * s;
    out[n * 4 + 2] = e2 * s;
    out[n * 4 + 3] = e3 * s;
  }
}

// ---------------- host ----------------

extern "C" void kernel_launch(void* const* d_in, const int* in_sizes, int n_in,
                              void* d_out, int out_size, void* d_ws, size_t ws_size,
                              hipStream_t stream) {
  const float* x   = (const float*)d_in[0];
  const int*   ei  = (const int*)d_in[1];
  const float* ea  = (const float*)d_in[2];
  const float* Wp  = (const float*)d_in[3];
  const float* bp  = (const float*)d_in[4];
  const float* W1  = (const float*)d_in[5];
  const float* We1 = (const float*)d_in[6];
  const float* as1 = (const float*)d_in[7];
  const float* ad1 = (const float*)d_in[8];
  const float* ae1 = (const float*)d_in[9];
  const float* b1  = (const float*)d_in[10];
  const float* W2  = (const float*)d_in[11];
  const float* We2 = (const float*)d_in[12];
  const float* as2 = (const float*)d_in[13];
  const float* ad2 = (const float*)d_in[14];
  const float* ae2 = (const float*)d_in[15];
  const float* b2  = (const float*)d_in[16];
  const float* W3  = (const float*)d_in[17];
  const float* We3 = (const float*)d_in[18];
  const float* as3 = (const float*)d_in[19];
  const float* ad3 = (const float*)d_in[20];
  const float* ae3 = (const float*)d_in[21];
  const float* b3  = (const float*)d_in[22];
  const float* Wc  = (const float*)d_in[23];
  const float* bc  = (const float*)d_in[24];
  float* out = (float*)d_out;

  const int* src = ei;
  const int* dst = ei + N_EDGES;

  char* wptr = (char*)d_ws;
  auto alloc = [&](size_t bytes) {
    char* p = wptr;
    wptr += (bytes + 255) & ~(size_t)255;
    return p;
  };
  int*            cnt      = (int*)alloc((size_t)N_NODES * 4);
  int*            row_ptr  = (int*)alloc((size_t)(N_NODES + 1) * 4);
  int*            row_next = (int*)alloc((size_t)N_NODES * 4);
  int*            csr_eid  = (int*)alloc((size_t)N_EDGES * 4);
  int*            csr_src  = (int*)alloc((size_t)N_EDGES * 4);
  float*          edot1    = (float*)alloc((size_t)4 * N_EDGES * 4);
  float*          edot2    = (float*)alloc((size_t)4 * N_EDGES * 4);
  float*          edot3    = (float*)alloc((size_t)N_EDGES * 4);
  unsigned short* hA_bf    = (unsigned short*)alloc((size_t)N_NODES * 256 * 2);
  unsigned short* hX_bf    = (unsigned short*)alloc((size_t)N_NODES * 256 * 2);
  float*          alp_s    = (float*)alloc((size_t)N_NODES * 4 * 4);
  float*          alp_d    = (float*)alloc((size_t)N_NODES * 4 * 4);
  unsigned short* Bt1      = (unsigned short*)alloc((size_t)64 * 256 * 2);
  unsigned short* Bt2      = (unsigned short*)alloc((size_t)256 * 256 * 2);
  unsigned short* Bt3      = (unsigned short*)alloc((size_t)256 * 64 * 2);

  // ---- CSR build ----
  hipMemsetAsync(cnt, 0, (size_t)N_NODES * 4, stream);
  hist_kernel<<<(N_EDGES + 255) / 256, 256, 0, stream>>>(dst, cnt, N_EDGES);
  scan_kernel<<<1, 1024, 0, stream>>>(cnt, row_ptr, row_next, N_NODES);
  fill_kernel<<<(N_EDGES + 255) / 256, 256, 0, stream>>>(dst, row_next, csr_eid, N_EDGES);

  // ---- prep (in_proj + weight cast + edge prep in one dispatch) ----
  prep_all_kernel<<<5384 + (N_EDGES + 255) / 256, 256, 0, stream>>>(
      x, Wp, bp, hA_bf, W1, W2, W3, Bt1, Bt2, Bt3,
      We1, ae1, We2, ae2, We3, ae3, csr_eid, src, ea, csr_src, edot1, edot2, edot3);

  dim3 g256(4, (N_NODES + 63) / 64);
  dim3 g64(1, (N_NODES + 63) / 64);

  // ---- layer 1: 64 -> 4x64, ELU ----
  mfma_gemm_alpha_kernel<64><<<g256, 256, 0, stream>>>(hA_bf, Bt1, hX_bf, as1, ad1,
                                                       alp_s, alp_d, N_NODES, 256);
  softagg4_kernel<true><<<N_NODES, 256, 0, stream>>>(row_ptr, csr_src, edot1,
                                                     alp_s, alp_d, hX_bf, b1, nullptr, hA_bf);

  // ---- layer 2: 256 -> 4x64, ELU ----
  mfma_gemm_alpha_kernel<256><<<g256, 256, 0, stream>>>(hA_bf, Bt2, hX_bf, as2, ad2,
                                                        alp_s, alp_d, N_NODES, 256);
  softagg4_kernel<true><<<N_NODES, 256, 0, stream>>>(row_ptr, csr_src, edot2,
                                                     alp_s, alp_d, hX_bf, b2, nullptr, hA_bf);

  // ---- layer 3: 256 -> 1x64 + classifier + softmax ----
  mfma_gemm_alpha_kernel<256><<<g64, 256, 0, stream>>>(hA_bf, Bt3, hX_bf, as3, ad3,
                                                       alp_s, alp_d, N_NODES, 64);
  softagg_cls_kernel<<<(N_NODES + 3) / 4, 256, 0, stream>>>(row_ptr, csr_src, edot3,
                                                            alp_s, alp_d, hX_bf, b3, Wc, bc,
                                                            out, N_NODES);
}

// Round 13
// 377.450 us; speedup vs baseline: 1.0653x; 1.0653x over previous
//
#include <hip/hip_runtime.h>
#include <math.h>

#define N_NODES 20000
#define N_EDGES 640000

typedef __attribute__((ext_vector_type(8))) short short8;
typedef __attribute__((ext_vector_type(4))) float floatx4;
typedef __attribute__((ext_vector_type(2))) float float2v;

__device__ __forceinline__ float elu_f(float v) { return v > 0.f ? v : expm1f(v); }

__device__ __forceinline__ unsigned short bf16_rne(float f) {
  union { float f; unsigned u; } v;
  v.f = f;
  unsigned r = v.u + 0x7FFF + ((v.u >> 16) & 1);
  return (unsigned short)(r >> 16);
}

// unpack a dword holding two bf16 (lo = elem0, hi = elem1) into packed f32 pair
__device__ __forceinline__ float2v unpack_bf2(unsigned u) {
  union { unsigned u; float f; } lo, hi;
  lo.u = u << 16;
  hi.u = u & 0xffff0000u;
  return (float2v){lo.f, hi.f};
}

// bank-swizzle within 8-element groups (writer 8-strided and reader both conflict-free)
__device__ __forceinline__ int swz(int c) {
  return (c & ~7) | ((((c & 7) + ((c >> 3) >> 2))) & 7);
}

// ---------------- CSR build ----------------

__global__ void hist_kernel(const int* __restrict__ dst, int* __restrict__ cnt, int ne) {
  int e = blockIdx.x * 256 + threadIdx.x;
  if (e < ne) atomicAdd(&cnt[dst[e]], 1);
}

__global__ __launch_bounds__(1024) void scan_kernel(const int* __restrict__ cnt,
                                                    int* __restrict__ row_ptr,
                                                    int* __restrict__ row_next, int n) {
  __shared__ int part[1024];
  int t = threadIdx.x;
  int per = (n + 1023) / 1024;   // 20 for n=20000
  int base = t * per;
  int v[20];
  // vectorized int4 loads (per=20 -> 5 x int4; base byte offset t*80, 16B aligned)
  if (base + per <= n) {
    #pragma unroll
    for (int q = 0; q < 5; ++q) {
      int4 u = *(const int4*)(cnt + base + q * 4);
      v[q * 4 + 0] = u.x; v[q * 4 + 1] = u.y; v[q * 4 + 2] = u.z; v[q * 4 + 3] = u.w;
    }
  } else {
    #pragma unroll
    for (int i = 0; i < 20; ++i) v[i] = (base + i < n) ? cnt[base + i] : 0;
  }
  int local = 0;
  #pragma unroll
  for (int i = 0; i < 20; ++i) local += v[i];
  part[t] = local;
  __syncthreads();
  for (int off = 1; off < 1024; off <<= 1) {
    int pv = (t >= off) ? part[t - off] : 0;
    __syncthreads();
    part[t] += pv;
    __syncthreads();
  }
  int prefix = (t == 0) ? 0 : part[t - 1];
  #pragma unroll
  for (int i = 0; i < 20; ++i) {
    int idx = base + i;
    if (idx < n) {
      row_ptr[idx] = prefix;
      row_next[idx] = prefix;
      prefix += v[i];
    }
  }
  if (t == 1023) row_ptr[n] = part[1023];
}

__global__ void fill_kernel(const int* __restrict__ dst, int* __restrict__ row_next,
                            int* __restrict__ csr_eid, int ne) {
  int e = blockIdx.x * 256 + threadIdx.x;
  if (e >= ne) return;
  int pos = atomicAdd(&row_next[dst[e]], 1);
  csr_eid[pos] = e;
}

// ---------------- prep_all: in_proj (0..4999) + wt cast (5000..5383) + edge prep (5384+) ---
// edot: planar [9][E] (per-wave coalesced reads in softagg phase 1).

__global__ void prep_all_kernel(const float* __restrict__ x, const float* __restrict__ Wp,
                                const float* __restrict__ bp, unsigned short* __restrict__ h_bf,
                                const float* __restrict__ W1, const float* __restrict__ W2,
                                const float* __restrict__ W3, unsigned short* __restrict__ Bt1,
                                unsigned short* __restrict__ Bt2, unsigned short* __restrict__ Bt3,
                                const float* __restrict__ We1, const float* __restrict__ ae1,
                                const float* __restrict__ We2, const float* __restrict__ ae2,
                                const float* __restrict__ We3, const float* __restrict__ ae3,
                                const int* __restrict__ csr_eid, const int* __restrict__ src,
                                const float* __restrict__ ea, int* __restrict__ csr_src,
                                float* __restrict__ edot) {
  int b = blockIdx.x, t = threadIdx.x;
  if (b < 5000) {
    int i = b * 256 + t;
    int node = i >> 6, c = i & 63;
    float v = x[node * 2] * Wp[c] + x[node * 2 + 1] * Wp[64 + c] + bp[c];
    h_bf[i] = bf16_rne(elu_f(v));
  } else if (b < 5384) {
    int idx = (b - 5000) * 256 + t;
    const float* W; unsigned short* Bt; int K, Nc, local;
    if (idx < 16384)      { W = W1; Bt = Bt1; K = 64;  Nc = 256; local = idx; }
    else if (idx < 81920) { W = W2; Bt = Bt2; K = 256; Nc = 256; local = idx - 16384; }
    else if (idx < 98304) { W = W3; Bt = Bt3; K = 256; Nc = 64;  local = idx - 81920; }
    else return;
    int k = local / Nc, n = local - k * Nc;
    Bt[(size_t)n * K + k] = bf16_rne(W[local]);
  } else {
    __shared__ float pj[27];
    if (t < 12) {
      int d = t >> 2, h = t & 3;
      float s = 0.f;
      for (int c = 0; c < 64; ++c) s += We1[d * 256 + h * 64 + c] * ae1[h * 64 + c];
      pj[t] = s;
    } else if (t < 24) {
      int u = t - 12; int d = u >> 2, h = u & 3;
      float s = 0.f;
      for (int c = 0; c < 64; ++c) s += We2[d * 256 + h * 64 + c] * ae2[h * 64 + c];
      pj[12 + u] = s;
    } else if (t < 27) {
      int d = t - 24;
      float s = 0.f;
      for (int c = 0; c < 64; ++c) s += We3[d * 64 + c] * ae3[c];
      pj[24 + d] = s;
    }
    __syncthreads();
    int i = (b - 5384) * 256 + t;
    if (i >= N_EDGES) return;
    int eid = csr_eid[i];
    csr_src[i] = src[eid];
    float e0 = ea[eid * 3 + 0], e1 = ea[eid * 3 + 1], e2 = ea[eid * 3 + 2];
    #pragma unroll
    for (int h = 0; h < 4; ++h)
      edot[(size_t)h * N_EDGES + i] = e0 * pj[h] + e1 * pj[4 + h] + e2 * pj[8 + h];
    #pragma unroll
    for (int h = 0; h < 4; ++h)
      edot[(size_t)(4 + h) * N_EDGES + i] = e0 * pj[12 + h] + e1 * pj[16 + h] + e2 * pj[20 + h];
    edot[(size_t)8 * N_EDGES + i] = e0 * pj[24] + e1 * pj[25] + e2 * pj[26];
  }
}

// ---------------- MFMA bf16 GEMM + fused alpha epilogue ----------------------------

template <int KDIM>
__global__ __launch_bounds__(256) void mfma_gemm_alpha_kernel(
    const unsigned short* __restrict__ A, const unsigned short* __restrict__ Bt,
    unsigned short* __restrict__ C_bf, const float* __restrict__ a_src,
    const float* __restrict__ a_dst, float* __restrict__ alp_s,
    float* __restrict__ alp_d, int M, int Nc) {
  __shared__ unsigned short As[64][40];
  __shared__ unsigned short Bs[64][40];
  int t = threadIdx.x;
  int wave = t >> 6, lane = t & 63;
  int m_frag = lane & 15, quad = lane >> 4;
  int row0 = blockIdx.y * 64, col0 = blockIdx.x * 64;
  int lr = t >> 2;
  int lk = (t & 3) * 8;
  floatx4 acc[4];
  #pragma unroll
  for (int c = 0; c < 4; ++c) acc[c] = (floatx4){0.f, 0.f, 0.f, 0.f};

  for (int k0 = 0; k0 < KDIM; k0 += 32) {
    int gr = row0 + lr;
    short8 av = {0, 0, 0, 0, 0, 0, 0, 0};
    if (gr < M) av = *(const short8*)(A + (size_t)gr * KDIM + k0 + lk);
    *(short8*)(&As[lr][lk]) = av;
    short8 bv = *(const short8*)(Bt + (size_t)(col0 + lr) * KDIM + k0 + lk);
    *(short8*)(&Bs[lr][lk]) = bv;
    __syncthreads();
    short8 a = *(const short8*)(&As[wave * 16 + m_frag][quad * 8]);
    #pragma unroll
    for (int c = 0; c < 4; ++c) {
      short8 b = *(const short8*)(&Bs[c * 16 + m_frag][quad * 8]);
      acc[c] = __builtin_amdgcn_mfma_f32_16x16x32_bf16(a, b, acc[c], 0, 0, 0);
    }
    __syncthreads();
  }

  int H = Nc >> 6;
  int head = blockIdx.x;
  float ps[4] = {}, pd[4] = {};
  #pragma unroll
  for (int c = 0; c < 4; ++c) {
    float asv = a_src[head * 64 + c * 16 + m_frag];
    float adv = a_dst[head * 64 + c * 16 + m_frag];
    #pragma unroll
    for (int i = 0; i < 4; ++i) {
      ps[i] += acc[c][i] * asv;
      pd[i] += acc[c][i] * adv;
    }
  }
  #pragma unroll
  for (int off = 1; off < 16; off <<= 1) {
    #pragma unroll
    for (int i = 0; i < 4; ++i) {
      ps[i] += __shfl_xor(ps[i], off);
      pd[i] += __shfl_xor(pd[i], off);
    }
  }
  #pragma unroll
  for (int c = 0; c < 4; ++c) {
    #pragma unroll
    for (int i = 0; i < 4; ++i) {
      int gr = row0 + wave * 16 + quad * 4 + i;
      if (gr < M) C_bf[(size_t)gr * Nc + col0 + c * 16 + m_frag] = bf16_rne(acc[c][i]);
    }
  }
  if (m_frag == 0) {
    #pragma unroll
    for (int i = 0; i < 4; ++i) {
      int gr = row0 + wave * 16 + quad * 4 + i;
      if (gr < M) {
        alp_s[gr * H + head] = ps[i];
        alp_d[gr * H + head] = pd[i];
      }
    }
  }
}

// ---------------- fused softmax + aggregate, H=4 (block per node) -------------------
// R11 configuration (best measured): phase 1 wave-per-head stride-64 (parallel loads
// beat per-edge instruction minimization — R12 post-mortem); single-pass exp;
// phase 2 L=32, S=8, accp[4], 2-edge unroll.

template <bool OUT_BF>
__global__ __launch_bounds__(256) void softagg4_kernel(
    const int* __restrict__ row_ptr, const int* __restrict__ csr_src,
    const float* __restrict__ edot, const float* __restrict__ alp_s,
    const float* __restrict__ alp_d, const unsigned short* __restrict__ xh_bf,
    const float* __restrict__ bias, float* __restrict__ out,
    unsigned short* __restrict__ out_bf) {
  constexpr int HC = 256, H = 4, CHUNK = 256, L = 32, S = 8;
  __shared__ float lds_w[H][CHUNK + 8];   // +8: heads hit distinct banks in phase 2
  __shared__ int lds_src[CHUNK];
  __shared__ float sh_inv[H];
  __shared__ float red[4 * HC];

  int n = blockIdx.x;
  int t = threadIdx.x;
  int wave = t >> 6, lane = t & 63;
  int slot = t / L, l = t % L;          // 8 slots x 32 lanes; lane covers ch [l*8, l*8+8)
  int head2 = l >> 3;
  int s0 = row_ptr[n], s1 = row_ptr[n + 1];

  float s_run = 0.f;
  float2v accp[4] = {};
  float adv = alp_d[n * H + wave];
  const float* __restrict__ edot_h = edot + (size_t)wave * N_EDGES;

  for (int c0 = s0; c0 < s1; c0 += CHUNK) {
    int cend = min(s1, c0 + CHUNK);
    {
      float se = 0.f;
      for (int i = c0 + lane; i < cend; i += 64) {
        int s = csr_src[i];
        if (wave == 0) lds_src[i - c0] = s;
        float a = alp_s[s * H + wave] + adv + edot_h[i];
        a = a > 0.f ? a : 0.2f * a;
        float w = __expf(fminf(a, 30.f));
        lds_w[wave][i - c0] = w;
        se += w;
      }
      #pragma unroll
      for (int off = 1; off < 64; off <<= 1) se += __shfl_xor(se, off);
      s_run += se;
    }
    __syncthreads();
    // 2-edge unrolled gather: two loads in flight per thread
    int i = c0 + slot;
    for (; i + S < cend; i += 2 * S) {
      int sA = lds_src[i - c0];
      int sB = lds_src[i - c0 + S];
      float wA = lds_w[head2][i - c0];
      float wB = lds_w[head2][i - c0 + S];
      uint4 uA = *(const uint4*)(xh_bf + (size_t)sA * HC + l * 8);
      uint4 uB = *(const uint4*)(xh_bf + (size_t)sB * HC + l * 8);
      float2v wAp = {wA, wA}, wBp = {wB, wB};
      accp[0] = __builtin_elementwise_fma(unpack_bf2(uA.x), wAp, accp[0]);
      accp[1] = __builtin_elementwise_fma(unpack_bf2(uA.y), wAp, accp[1]);
      accp[2] = __builtin_elementwise_fma(unpack_bf2(uA.z), wAp, accp[2]);
      accp[3] = __builtin_elementwise_fma(unpack_bf2(uA.w), wAp, accp[3]);
      accp[0] = __builtin_elementwise_fma(unpack_bf2(uB.x), wBp, accp[0]);
      accp[1] = __builtin_elementwise_fma(unpack_bf2(uB.y), wBp, accp[1]);
      accp[2] = __builtin_elementwise_fma(unpack_bf2(uB.z), wBp, accp[2]);
      accp[3] = __builtin_elementwise_fma(unpack_bf2(uB.w), wBp, accp[3]);
    }
    if (i < cend) {
      int s = lds_src[i - c0];
      float w = lds_w[head2][i - c0];
      uint4 u = *(const uint4*)(xh_bf + (size_t)s * HC + l * 8);
      float2v wp = {w, w};
      accp[0] = __builtin_elementwise_fma(unpack_bf2(u.x), wp, accp[0]);
      accp[1] = __builtin_elementwise_fma(unpack_bf2(u.y), wp, accp[1]);
      accp[2] = __builtin_elementwise_fma(unpack_bf2(u.z), wp, accp[2]);
      accp[3] = __builtin_elementwise_fma(unpack_bf2(u.w), wp, accp[3]);
    }
    __syncthreads();
  }
  if (lane == 0) sh_inv[wave] = 1.0f / (s_run + 1e-16f);
  __syncthreads();
  float2v invp = {sh_inv[head2], sh_inv[head2]};
  #pragma unroll
  for (int d = 0; d < 4; ++d) accp[d] *= invp;
  float accf[8];
  #pragma unroll
  for (int d = 0; d < 4; ++d) { accf[2 * d] = accp[d].x; accf[2 * d + 1] = accp[d].y; }
  // reduce slots within wave (slots stride L=32 lanes)
  #pragma unroll
  for (int off = L; off < 64; off <<= 1) {
    #pragma unroll
    for (int j = 0; j < 8; ++j) accf[j] += __shfl_xor(accf[j], off);
  }
  if (lane < L) {
    #pragma unroll
    for (int j = 0; j < 8; ++j) red[wave * HC + swz(lane * 8 + j)] = accf[j];
  }
  __syncthreads();
  {
    int pos = swz(t);
    float a = red[0 * HC + pos] + red[1 * HC + pos] + red[2 * HC + pos] + red[3 * HC + pos];
    a += bias[t];
    a = elu_f(a);
    if (OUT_BF) out_bf[(size_t)n * HC + t] = bf16_rne(a);
    else out[(size_t)n * HC + t] = a;
  }
}

// ---------------- layer-3 softagg (wave per node, H=1, HC=64) + fused classifier ----

__global__ __launch_bounds__(256) void softagg_cls_kernel(
    const int* __restrict__ row_ptr, const int* __restrict__ csr_src,
    const float* __restrict__ edot, const float* __restrict__ alp_s,
    const float* __restrict__ alp_d, const unsigned short* __restrict__ xh_bf,
    const float* __restrict__ b3, const float* __restrict__ Wc,
    const float* __restrict__ bc, float* __restrict__ out, int n_nodes) {
  constexpr int CHUNK = 256;
  __shared__ float lds_w[4][CHUNK];
  __shared__ int lds_s[4][CHUNK];

  int wave = threadIdx.x >> 6, lane = threadIdx.x & 63;
  int n = blockIdx.x * 4 + wave;
  if (n >= n_nodes) return;
  int slot = lane >> 3, l = lane & 7;
  int s0 = row_ptr[n], s1 = row_ptr[n + 1];

  float s_run = 0.f;
  float2v accp[4] = {};
  float adv = alp_d[n];

  for (int c0 = s0; c0 < s1; c0 += CHUNK) {
    int cend = min(s1, c0 + CHUNK);
    float se = 0.f;
    for (int i = c0 + lane; i < cend; i += 64) {
      int s = csr_src[i];
      lds_s[wave][i - c0] = s;
      float a = alp_s[s] + adv + edot[i];
      a = a > 0.f ? a : 0.2f * a;
      float w = __expf(fminf(a, 30.f));
      lds_w[wave][i - c0] = w;
      se += w;
    }
    #pragma unroll
    for (int off = 1; off < 64; off <<= 1) se += __shfl_xor(se, off);
    s_run += se;
    // 2-edge unrolled gather
    int i = c0 + slot;
    for (; i + 8 < cend; i += 16) {
      int sA = lds_s[wave][i - c0];
      int sB = lds_s[wave][i - c0 + 8];
      float wA = lds_w[wave][i - c0];
      float wB = lds_w[wave][i - c0 + 8];
      uint4 uA = *(const uint4*)(xh_bf + (size_t)sA * 64 + l * 8);
      uint4 uB = *(const uint4*)(xh_bf + (size_t)sB * 64 + l * 8);
      float2v wAp = {wA, wA}, wBp = {wB, wB};
      accp[0] = __builtin_elementwise_fma(unpack_bf2(uA.x), wAp, accp[0]);
      accp[1] = __builtin_elementwise_fma(unpack_bf2(uA.y), wAp, accp[1]);
      accp[2] = __builtin_elementwise_fma(unpack_bf2(uA.z), wAp, accp[2]);
      accp[3] = __builtin_elementwise_fma(unpack_bf2(uA.w), wAp, accp[3]);
      accp[0] = __builtin_elementwise_fma(unpack_bf2(uB.x), wBp, accp[0]);
      accp[1] = __builtin_elementwise_fma(unpack_bf2(uB.y), wBp, accp[1]);
      accp[2] = __builtin_elementwise_fma(unpack_bf2(uB.z), wBp, accp[2]);
      accp[3] = __builtin_elementwise_fma(unpack_bf2(uB.w), wBp, accp[3]);
    }
    if (i < cend) {
      int s = lds_s[wave][i - c0];
      float w = lds_w[wave][i - c0];
      uint4 u = *(const uint4*)(xh_bf + (size_t)s * 64 + l * 8);
      float2v wp = {w, w};
      accp[0] = __builtin_elementwise_fma(unpack_bf2(u.x), wp, accp[0]);
      accp[1] = __builtin_elementwise_fma(unpack_bf2(u.y), wp, accp[1]);
      accp[2] = __builtin_elementwise_fma(unpack_bf2(u.z), wp, accp[2]);
      accp[3] = __builtin_elementwise_fma(unpack_bf2(u.w), wp, accp[3]);
    }
  }
  float inv = 1.0f / (s_run + 1e-16f);
  float2v invp = {inv, inv};
  #pragma unroll
  for (int d = 0; d < 4; ++d) accp[d] *= invp;
  float accf[8];
  #pragma unroll
  for (int d = 0; d < 4; ++d) { accf[2 * d] = accp[d].x; accf[2 * d + 1] = accp[d].y; }
  #pragma unroll
  for (int off = 8; off < 64; off <<= 1) {
    #pragma unroll
    for (int j = 0; j < 8; ++j) accf[j] += __shfl_xor(accf[j], off);
  }
  float p0 = 0.f, p1 = 0.f, p2 = 0.f, p3 = 0.f;
  #pragma unroll
  for (int j = 0; j < 8; ++j) {
    int c = l * 8 + j;
    float v = accf[j] + b3[c];
    p0 += v * Wc[c * 4 + 0];
    p1 += v * Wc[c * 4 + 1];
    p2 += v * Wc[c * 4 + 2];
    p3 += v * Wc[c * 4 + 3];
  }
  #pragma unroll
  for (int off = 1; off < 8; off <<= 1) {
    p0 += __shfl_xor(p0, off);
    p1 += __shfl_xor(p1, off);
    p2 += __shfl_xor(p2, off);
    p3 += __shfl_xor(p3, off);
  }
  if (lane == 0) {
    p0 += bc[0]; p1 += bc[1]; p2 += bc[2]; p3 += bc[3];
    float mx = fmaxf(fmaxf(p0, p1), fmaxf(p2, p3));
    float e0 = __expf(p0 - mx), e1 = __expf(p1 - mx), e2 = __expf(p2 - mx), e3 = __expf(p3 - mx);
    float s = 1.f / (e0 + e1 + e2 + e3);
    out[n * 4 + 0] = e0 * s;
    out[n * 4 + 1] = e1 * s;
    out[n * 4 + 2] = e2 * s;
    out[n * 4 + 3] = e3 * s;
  }
}

// ---------------- host ----------------

extern "C" void kernel_launch(void* const* d_in, const int* in_sizes, int n_in,
                              void* d_out, int out_size, void* d_ws, size_t ws_size,
                              hipStream_t stream) {
  const float* x   = (const float*)d_in[0];
  const int*   ei  = (const int*)d_in[1];
  const float* ea  = (const float*)d_in[2];
  const float* Wp  = (const float*)d_in[3];
  const float* bp  = (const float*)d_in[4];
  const float* W1  = (const float*)d_in[5];
  const float* We1 = (const float*)d_in[6];
  const float* as1 = (const float*)d_in[7];
  const float* ad1 = (const float*)d_in[8];
  const float* ae1 = (const float*)d_in[9];
  const float* b1  = (const float*)d_in[10];
  const float* W2  = (const float*)d_in[11];
  const float* We2 = (const float*)d_in[12];
  const float* as2 = (const float*)d_in[13];
  const float* ad2 = (const float*)d_in[14];
  const float* ae2 = (const float*)d_in[15];
  const float* b2  = (const float*)d_in[16];
  const float* W3  = (const float*)d_in[17];
  const float* We3 = (const float*)d_in[18];
  const float* as3 = (const float*)d_in[19];
  const float* ad3 = (const float*)d_in[20];
  const float* ae3 = (const float*)d_in[21];
  const float* b3  = (const float*)d_in[22];
  const float* Wc  = (const float*)d_in[23];
  const float* bc  = (const float*)d_in[24];
  float* out = (float*)d_out;

  const int* src = ei;
  const int* dst = ei + N_EDGES;

  char* wptr = (char*)d_ws;
  auto alloc = [&](size_t bytes) {
    char* p = wptr;
    wptr += (bytes + 255) & ~(size_t)255;
    return p;
  };
  int*            cnt      = (int*)alloc((size_t)N_NODES * 4);
  int*            row_ptr  = (int*)alloc((size_t)(N_NODES + 1) * 4);
  int*            row_next = (int*)alloc((size_t)N_NODES * 4);
  int*            csr_eid  = (int*)alloc((size_t)N_EDGES * 4);
  int*            csr_src  = (int*)alloc((size_t)N_EDGES * 4);
  float*          edot     = (float*)alloc((size_t)9 * N_EDGES * 4);
  unsigned short* hA_bf    = (unsigned short*)alloc((size_t)N_NODES * 256 * 2);
  unsigned short* hX_bf    = (unsigned short*)alloc((size_t)N_NODES * 256 * 2);
  float*          alp_s    = (float*)alloc((size_t)N_NODES * 4 * 4);
  float*          alp_d    = (float*)alloc((size_t)N_NODES * 4 * 4);
  unsigned short* Bt1      = (unsigned short*)alloc((size_t)64 * 256 * 2);
  unsigned short* Bt2      = (unsigned short*)alloc((size_t)256 * 256 * 2);
  unsigned short* Bt3      = (unsigned short*)alloc((size_t)256 * 64 * 2);

  // ---- CSR build ----
  hipMemsetAsync(cnt, 0, (size_t)N_NODES * 4, stream);
  hist_kernel<<<(N_EDGES + 255) / 256, 256, 0, stream>>>(dst, cnt, N_EDGES);
  scan_kernel<<<1, 1024, 0, stream>>>(cnt, row_ptr, row_next, N_NODES);
  fill_kernel<<<(N_EDGES + 255) / 256, 256, 0, stream>>>(dst, row_next, csr_eid, N_EDGES);

  // ---- prep (in_proj + weight cast + edge prep in one dispatch) ----
  prep_all_kernel<<<5384 + (N_EDGES + 255) / 256, 256, 0, stream>>>(
      x, Wp, bp, hA_bf, W1, W2, W3, Bt1, Bt2, Bt3,
      We1, ae1, We2, ae2, We3, ae3, csr_eid, src, ea, csr_src, edot);

  dim3 g256(4, (N_NODES + 63) / 64);
  dim3 g64(1, (N_NODES + 63) / 64);

  // ---- layer 1: 64 -> 4x64, ELU ----
  mfma_gemm_alpha_kernel<64><<<g256, 256, 0, stream>>>(hA_bf, Bt1, hX_bf, as1, ad1,
                                                       alp_s, alp_d, N_NODES, 256);
  softagg4_kernel<true><<<N_NODES, 256, 0, stream>>>(row_ptr, csr_src,
                                                     edot + (size_t)0 * N_EDGES,
                                                     alp_s, alp_d, hX_bf, b1, nullptr, hA_bf);

  // ---- layer 2: 256 -> 4x64, ELU ----
  mfma_gemm_alpha_kernel<256><<<g256, 256, 0, stream>>>(hA_bf, Bt2, hX_bf, as2, ad2,
                                                        alp_s, alp_d, N_NODES, 256);
  softagg4_kernel<true><<<N_NODES, 256, 0, stream>>>(row_ptr, csr_src,
                                                     edot + (size_t)4 * N_EDGES,
                                                     alp_s, alp_d, hX_bf, b2, nullptr, hA_bf);

  // ---- layer 3: 256 -> 1x64 + classifier + softmax ----
  mfma_gemm_alpha_kernel<256><<<g64, 256, 0, stream>>>(hA_bf, Bt3, hX_bf, as3, ad3,
                                                       alp_s, alp_d, N_NODES, 64);
  softagg_cls_kernel<<<(N_NODES + 3) / 4, 256, 0, stream>>>(row_ptr, csr_src,
                                                            edot + (size_t)8 * N_EDGES,
                                                            alp_s, alp_d, hX_bf, b3, Wc, bc,
                                                            out, N_NODES);
}